// Round 12
// baseline (313.223 us; speedup 1.0000x reference)
//
#include <hip/hip_runtime.h>

#define N_PTS   200000
#define N_EDGES 1600000
#define MEM_SIZE (1 << 27)
#define NF4     (MEM_SIZE / 4)            // 33,554,432 float4
#define HALF4   (NF4 / 2)                 // 16,777,216

#define NPARTS  25                        // node parts of 8192
#define PSHIFT  13
#define PSIZE   8192
#define NSLICE  20                        // edge slices of 80000
#define SLICE_E 80000
#define BLK_E   3200                      // edges per K1 block (25 blocks/slice)
#define BLK_I4  1600
#define K1_BLK  500
#define K2_BLK  512
#define NBUCKET (NSLICE * NPARTS)         // 500
#define BCAP    8192                      // bucket capacity (mean 6400, sigma ~80)
#define RECS_PB (BLK_E * 2)               // 6400 records per K1 block

// ws layout: gCur[500] u32 | gBuk[500*8192] u32 (16MB) | pair[204800] u64 (1.6MB)

__global__ void k0_zero(unsigned* __restrict__ gCur) {
    int t = threadIdx.x;
    if (t < NBUCKET) gCur[t] = 0;
}

// K1: bin half-edges into (slice, part) buckets + copy first half of mem.
// Each half-edge is written ONCE (u32 record), coalesced per bucket run.
__global__ __launch_bounds__(1024) void k1_copy_bin(const float4* __restrict__ src,
                                                    float4* __restrict__ dst,
                                                    const int4* __restrict__ edges4,
                                                    unsigned* __restrict__ gCur,
                                                    unsigned* __restrict__ gBuk) {
    __shared__ unsigned cnt[NPARTS];
    __shared__ unsigned cnt2[NPARTS];
    __shared__ unsigned base_l[NPARTS];
    __shared__ unsigned gbase[NPARTS];
    __shared__ unsigned buf[RECS_PB];

    int b = blockIdx.x, t = threadIdx.x;
    if (t < NPARTS) { cnt[t] = 0; cnt2[t] = 0; }
    __syncthreads();

    int s   = b / 25;                     // slice id
    int li0 = (b % 25) * BLK_E;           // local edge base within slice

    // stash this block's edges in registers (all reads L2-friendly, once)
    int4 pA = edges4[b * BLK_I4 + t];
    bool hasB = t < (BLK_I4 - 1024);      // t < 576
    int4 pB;
    if (hasB) pB = edges4[b * BLK_I4 + 1024 + t];

    // count phase
    atomicAdd(&cnt[pA.x >> PSHIFT], 1u);
    atomicAdd(&cnt[pA.y >> PSHIFT], 1u);
    atomicAdd(&cnt[pA.z >> PSHIFT], 1u);
    atomicAdd(&cnt[pA.w >> PSHIFT], 1u);
    if (hasB) {
        atomicAdd(&cnt[pB.x >> PSHIFT], 1u);
        atomicAdd(&cnt[pB.y >> PSHIFT], 1u);
        atomicAdd(&cnt[pB.z >> PSHIFT], 1u);
        atomicAdd(&cnt[pB.w >> PSHIFT], 1u);
    }
    __syncthreads();

    if (t == 0) {                         // exclusive prefix over 25 counters
        unsigned run = 0;
        for (int p = 0; p < NPARTS; ++p) { base_l[p] = run; run += cnt[p]; }
    }
    if (t < NPARTS)                        // reserve global bucket space
        gbase[t] = atomicAdd(&gCur[s * NPARTS + t], cnt[t]);
    __syncthreads();

    // scatter into LDS buffer ordered by part
    {
        unsigned li = (unsigned)(li0 + 2 * t);
        unsigned r0 = ((unsigned)(pA.x & (PSIZE - 1)) << 19) >> 1;  // placeholder avoided below
        // record = node_local<<18 | flag<<17 | local_idx(17b)
        unsigned p, pos;
        p = pA.x >> PSHIFT; pos = atomicAdd(&cnt2[p], 1u);
        buf[base_l[p] + pos] = ((unsigned)(pA.x & (PSIZE - 1)) << 18) | li;
        p = pA.y >> PSHIFT; pos = atomicAdd(&cnt2[p], 1u);
        buf[base_l[p] + pos] = ((unsigned)(pA.y & (PSIZE - 1)) << 18) | (1u << 17) | li;
        p = pA.z >> PSHIFT; pos = atomicAdd(&cnt2[p], 1u);
        buf[base_l[p] + pos] = ((unsigned)(pA.z & (PSIZE - 1)) << 18) | (li + 1u);
        p = pA.w >> PSHIFT; pos = atomicAdd(&cnt2[p], 1u);
        buf[base_l[p] + pos] = ((unsigned)(pA.w & (PSIZE - 1)) << 18) | (1u << 17) | (li + 1u);
        if (hasB) {
            unsigned lj = (unsigned)(li0 + 2 * (1024 + t));
            p = pB.x >> PSHIFT; pos = atomicAdd(&cnt2[p], 1u);
            buf[base_l[p] + pos] = ((unsigned)(pB.x & (PSIZE - 1)) << 18) | lj;
            p = pB.y >> PSHIFT; pos = atomicAdd(&cnt2[p], 1u);
            buf[base_l[p] + pos] = ((unsigned)(pB.y & (PSIZE - 1)) << 18) | (1u << 17) | lj;
            p = pB.z >> PSHIFT; pos = atomicAdd(&cnt2[p], 1u);
            buf[base_l[p] + pos] = ((unsigned)(pB.z & (PSIZE - 1)) << 18) | (lj + 1u);
            p = pB.w >> PSHIFT; pos = atomicAdd(&cnt2[p], 1u);
            buf[base_l[p] + pos] = ((unsigned)(pB.w & (PSIZE - 1)) << 18) | (1u << 17) | (lj + 1u);
        }
    }
    __syncthreads();

    // coalesced write-out, one contiguous run per part
    for (int p = 0; p < NPARTS; ++p) {
        unsigned c = cnt[p], bl = base_l[p], gb = gbase[p];
        unsigned dbase = ((unsigned)(s * NPARTS + p) << PSHIFT) + gb;
        for (unsigned j = t; j < c; j += 1024)
            if (gb + j < BCAP) gBuk[dbase + j] = buf[bl + j];
    }

    // copy first half of mem (restrict allows the compiler to batch loads)
    #pragma unroll 4
    for (int ci = b * 1024 + t; ci < HALF4; ci += K1_BLK * 1024)
        dst[ci] = src[ci];
}

// K2: blocks 0..24 reduce one node-part each (every lane active, zero
// divergence waste, each record touched once); blocks 25..511 copy.
__global__ __launch_bounds__(1024) void k2_copy_min(const float4* __restrict__ src,
                                                    float4* __restrict__ dst,
                                                    const unsigned* __restrict__ gCur,
                                                    const unsigned* __restrict__ gBuk,
                                                    unsigned long long* __restrict__ pair) {
    __shared__ unsigned mn1[PSIZE];
    __shared__ unsigned mn2[PSIZE];
    int b = blockIdx.x, t = threadIdx.x;

    if (b < NPARTS) {
        for (int j = t; j < PSIZE; j += 1024) { mn1[j] = 0xFFFFFFFFu; mn2[j] = 0xFFFFFFFFu; }
        __syncthreads();
        for (int s = 0; s < NSLICE; ++s) {
            unsigned c = gCur[s * NPARTS + b];
            if (c > BCAP) c = BCAP;
            unsigned base = (unsigned)(s * NPARTS + b) << PSHIFT;
            for (unsigned j = t; j < c; j += 1024) {
                unsigned r  = gBuk[base + j];
                unsigned nl = r >> 18;
                unsigned h  = (unsigned)(s * SLICE_E) + (r & 0x1FFFFu)
                            + ((r >> 17) & 1u) * (unsigned)N_EDGES;
                unsigned old = atomicMin(&mn1[nl], h);
                unsigned cd = (h < old) ? old : h;
                if (cd != 0xFFFFFFFFu) atomicMin(&mn2[nl], cd);
            }
        }
        __syncthreads();
        for (int j = t; j < PSIZE; j += 1024) {
            int n = (b << PSHIFT) + j;
            if (n < N_PTS)
                pair[n] = ((unsigned long long)mn2[j] << 32) | (unsigned long long)mn1[j];
        }
    } else {
        int cb = b - NPARTS;
        #pragma unroll 4
        for (int ci = HALF4 + cb * 1024 + t; ci < NF4; ci += (K2_BLK - NPARTS) * 1024)
            dst[ci] = src[ci];
    }
}

__device__ __forceinline__ int quant6(float d) {
    // match jnp: clip(round((d + 1)/2 * 63), 0, 63); jnp.round = half-to-even -> rintf
    float x = ((d + 1.0f) / 2.0f) * 63.0f;
    float r = rintf(x);
    r = fminf(fmaxf(r, 0.0f), 63.0f);
    return (int)r;
}

__global__ void finalize(const float* __restrict__ pts, const float* __restrict__ tex,
                         const int2* __restrict__ edges,
                         const unsigned long long* __restrict__ pair,
                         float* __restrict__ out) {
    int n = blockIdx.x * blockDim.x + threadIdx.x;
    if (n >= N_PTS) return;

    unsigned long long pr = pair[n];
    unsigned k1 = (unsigned)(pr & 0xFFFFFFFFu);
    unsigned k2 = (unsigned)(pr >> 32);

    float px = pts[2 * n], py = pts[2 * n + 1];
    int t = (tex[n] > 0.7f) ? 1 : 0;

    int v0x = 0, v0y = 0, t0 = 0, v1x = 0, v1y = 0, t1 = 0;

    if (k1 < 2u * N_EDGES) {
        int k = (int)k1;
        int2 e = edges[(k < N_EDGES) ? k : (k - N_EDGES)];
        int dst = (k < N_EDGES) ? e.y : e.x;
        v0x = quant6(pts[2 * dst] - px);
        v0y = quant6(pts[2 * dst + 1] - py);
        t0 = (tex[dst] > 0.7f) ? 1 : 0;
    }
    if (k2 < 2u * N_EDGES) {
        int k = (int)k2;
        int2 e = edges[(k < N_EDGES) ? k : (k - N_EDGES)];
        int dst = (k < N_EDGES) ? e.y : e.x;
        v1x = quant6(pts[2 * dst] - px);
        v1y = quant6(pts[2 * dst + 1] - py);
        t1 = (tex[dst] > 0.7f) ? 1 : 0;
    }

    // hash keeps only cols 0..4 (col4 masked to 3 bits); each rel-variant
    // appears 6 times in rel_all (2 builds x 3 identity-rolls / 3 swap-rolls).
    int h_id = t | (v0x << 6) | (v0y << 12) | (t0 << 18) | ((v1x & 7) << 24);
    int h_sw = t | (v1x << 6) | (v1y << 12) | (t1 << 18) | ((v0x & 7) << 24);

    atomicAdd(&out[h_id], 6.0f);
    atomicAdd(&out[h_sw], 6.0f);
}

extern "C" void kernel_launch(void* const* d_in, const int* in_sizes, int n_in,
                              void* d_out, int out_size, void* d_ws, size_t ws_size,
                              hipStream_t stream) {
    const float* pts   = (const float*)d_in[0];
    const float* tex   = (const float*)d_in[1];
    const int2*  edges = (const int2*)d_in[2];   // int64 in ref -> int32 on device
    const float* mem   = (const float*)d_in[3];
    float*       out   = (float*)d_out;

    unsigned*           gCur = (unsigned*)d_ws;                       // 500 u32
    unsigned*           gBuk = gCur + 512;                            // 500*8192 u32 = 16MB
    unsigned long long* pair = (unsigned long long*)(gBuk + NBUCKET * BCAP); // 1.6MB

    k0_zero<<<1, 512, 0, stream>>>(gCur);
    k1_copy_bin<<<K1_BLK, 1024, 0, stream>>>(
        (const float4*)mem, (float4*)out, (const int4*)edges, gCur, gBuk);
    k2_copy_min<<<K2_BLK, 1024, 0, stream>>>(
        (const float4*)mem, (float4*)out, gCur, gBuk, pair);
    finalize<<<(N_PTS + 255) / 256, 256, 0, stream>>>(pts, tex, edges, pair, out);
}

// Round 13
// 261.391 us; speedup vs baseline: 1.1983x; 1.1983x over previous
//
#include <hip/hip_runtime.h>

#define N_PTS   200000
#define N_EDGES 1600000
#define MEM_SIZE (1 << 27)

#define NP   32                               // node parts
#define NPB  6400                             // nodes/part (32*6400 = 204800 >= 200000)
#define EP   16                               // edge slices; W = 16*200K*8B = 25.6 MB
#define EPS  (N_EDGES / EP)                   // 100000 edges per slice
#define EPS4 (EPS / 2)                        // 50000 int4 (2 edges) per slice
#define NBLK (NP * EP)                        // 512 blocks = exactly 2 per CU
#define NTHR 1024                             // 32 waves/CU with 2 blocks/CU (max occ)
#define NF4  (MEM_SIZE / 4)                   // 33,554,432 float4
#define CSTRIDE (NBLK * NTHR)                 // 524,288 threads -> 64 f4/thread exact
#define CITER (NF4 / CSTRIDE)                 // 64
#define SITER ((EPS4 + NTHR - 1) / NTHR)      // 49

__device__ __forceinline__ void upd2(unsigned* __restrict__ mn1, unsigned* __restrict__ mn2,
                                     int a, unsigned i) {
    if ((unsigned)a < NPB) {
        unsigned old = atomicMin(&mn1[a], i);
        unsigned c = (i < old) ? old : i;      // displaced value or losing insert
        if (c != 0xFFFFFFFFu) atomicMin(&mn2[a], c);
    }
}

__device__ __forceinline__ void proc(unsigned* __restrict__ mn1, unsigned* __restrict__ mn2,
                                     int lo, int4 p, int g /* global int4 index */) {
    // int4 g holds edges 2g (p.x,p.y) and 2g+1 (p.z,p.w)
    unsigned ia0 = (unsigned)(2 * g);
    unsigned ib0 = (unsigned)(2 * g + N_EDGES);
    upd2(mn1, mn2, p.x - lo, ia0);
    upd2(mn1, mn2, p.y - lo, ib0);
    upd2(mn1, mn2, p.z - lo, ia0 + 1u);
    upd2(mn1, mn2, p.w - lo, ib0 + 1u);
}

// Fused: out=mem copy (HBM-bound) + per-(slice,node-part) LDS 2-min scan.
// XCD-affine slice mapping: all 32 blocks scanning slice `ep` share one XCD
// (assuming the standard b%8 round-robin), so slice re-reads (800KB x2 per
// XCD < 4MB L2) are XCD-L2-local instead of contending with the copy's LLC/
// HBM stream. This was r11's dominant scan cost (~400MB of LLC re-reads).
__global__ __launch_bounds__(NTHR) void fused_copy_scan(const float4* __restrict__ src,
                                                        float4* __restrict__ dst,
                                                        const int4* __restrict__ edges4,
                                                        unsigned long long* __restrict__ W) {
    __shared__ unsigned mn1[NPB];
    __shared__ unsigned mn2[NPB];

    int b   = blockIdx.x;
    int xcd = b & 7;
    int ep  = (xcd << 1) | ((b >> 3) & 1);   // slices 2*xcd, 2*xcd+1 live on XCD xcd
    int np  = b >> 4;                        // 0..31
    int lo = np * NPB;
    int t  = threadIdx.x;

    for (int j = t; j < NPB; j += NTHR) { mn1[j] = 0xFFFFFFFFu; mn2[j] = 0xFFFFFFFFu; }
    __syncthreads();

    int q0 = ep * EPS4;              // slice start, int4 units
    int cbase = b * NTHR + t;        // copy index, stride CSTRIDE

    #pragma unroll 4
    for (int j = 0; j < CITER; ++j) {
        int ci = cbase + j * CSTRIDE;
        float4 v = src[ci];
        int k = t + j * NTHR;
        bool have = (j < SITER) && (k < EPS4);
        int4 p;
        if (have) p = edges4[q0 + k];
        dst[ci] = v;
        if (have) proc(mn1, mn2, lo, p, q0 + k);
    }
    __syncthreads();

    for (int j = t; j < NPB; j += NTHR) {
        int n = lo + j;
        if (n < N_PTS)
            W[(size_t)ep * N_PTS + n] =
                ((unsigned long long)mn2[j] << 32) | (unsigned long long)mn1[j];
    }
}

__device__ __forceinline__ int quant6(float d) {
    // match jnp: clip(round((d + 1)/2 * 63), 0, 63); jnp.round = half-to-even -> rintf
    float x = ((d + 1.0f) / 2.0f) * 63.0f;
    float r = rintf(x);
    r = fminf(fmaxf(r, 0.0f), 63.0f);
    return (int)r;
}

__global__ void finalize(const float* __restrict__ pts, const float* __restrict__ tex,
                         const int2* __restrict__ edges,
                         const unsigned long long* __restrict__ W,
                         float* __restrict__ out) {
    int n = blockIdx.x * blockDim.x + threadIdx.x;
    if (n >= N_PTS) return;

    // merge EP per-slice (m1,m2) pairs -> global two smallest (all indices distinct)
    unsigned int k1 = 0xFFFFFFFFu, k2 = 0xFFFFFFFFu;
    #pragma unroll
    for (int s = 0; s < EP; ++s) {
        unsigned long long pr = W[(size_t)s * N_PTS + n];
        unsigned int m1 = (unsigned int)(pr & 0xFFFFFFFFu);
        unsigned int m2 = (unsigned int)(pr >> 32);
        if (m1 < k1) { k2 = k1; k1 = m1; } else if (m1 < k2) { k2 = m1; }
        if (m2 < k2 && m2 > k1) { k2 = m2; }
    }

    float px = pts[2 * n], py = pts[2 * n + 1];
    int t = (tex[n] > 0.7f) ? 1 : 0;

    int v0x = 0, v0y = 0, t0 = 0, v1x = 0, v1y = 0, t1 = 0;

    if (k1 < 2u * N_EDGES) {
        int k = (int)k1;
        int2 e = edges[(k < N_EDGES) ? k : (k - N_EDGES)];
        int dst = (k < N_EDGES) ? e.y : e.x;
        v0x = quant6(pts[2 * dst] - px);
        v0y = quant6(pts[2 * dst + 1] - py);
        t0 = (tex[dst] > 0.7f) ? 1 : 0;
    }
    if (k2 < 2u * N_EDGES) {
        int k = (int)k2;
        int2 e = edges[(k < N_EDGES) ? k : (k - N_EDGES)];
        int dst = (k < N_EDGES) ? e.y : e.x;
        v1x = quant6(pts[2 * dst] - px);
        v1y = quant6(pts[2 * dst + 1] - py);
        t1 = (tex[dst] > 0.7f) ? 1 : 0;
    }

    // hash keeps only cols 0..4 (col4 masked to 3 bits); each rel-variant
    // appears 6 times in rel_all (2 builds x 3 identity-rolls / 3 swap-rolls).
    int h_id = t | (v0x << 6) | (v0y << 12) | (t0 << 18) | ((v1x & 7) << 24);
    int h_sw = t | (v1x << 6) | (v1y << 12) | (t1 << 18) | ((v0x & 7) << 24);

    atomicAdd(&out[h_id], 6.0f);
    atomicAdd(&out[h_sw], 6.0f);
}

extern "C" void kernel_launch(void* const* d_in, const int* in_sizes, int n_in,
                              void* d_out, int out_size, void* d_ws, size_t ws_size,
                              hipStream_t stream) {
    const float* pts   = (const float*)d_in[0];
    const float* tex   = (const float*)d_in[1];
    const int2*  edges = (const int2*)d_in[2];   // int64 in ref -> int32 on device
    const float* mem   = (const float*)d_in[3];
    float*       out   = (float*)d_out;

    unsigned long long* W = (unsigned long long*)d_ws;   // 16 * 200K * 8B = 25.6 MB

    fused_copy_scan<<<NBLK, NTHR, 0, stream>>>(
        (const float4*)mem, (float4*)out, (const int4*)edges, W);
    finalize<<<(N_PTS + 255) / 256, 256, 0, stream>>>(pts, tex, edges, W, out);
}

// Round 14
// 237.390 us; speedup vs baseline: 1.3194x; 1.1011x over previous
//
#include <hip/hip_runtime.h>

#define N_PTS   200000
#define N_EDGES 1600000
#define MEM_SIZE (1 << 27)

#define NP   16                               // node parts (halved vs r11)
#define NPB  12800                            // nodes/part; 102.4KB LDS -> 1 block/CU
#define EP   16                               // edge slices; W = 16*200K*8B = 25.6 MB
#define EPS  (N_EDGES / EP)                   // 100000 edges per slice
#define EPS4 (EPS / 2)                        // 50000 int4 (2 edges) per slice
#define NBLK (NP * EP)                        // 256 blocks = exactly 1 per CU
#define NTHR 1024                             // 16 waves/CU (LDS-capped occupancy)
#define NF4  (MEM_SIZE / 4)                   // 33,554,432 float4
#define CSTRIDE (NBLK * NTHR)                 // 262,144 threads -> 128 f4/thread exact
#define CITER (NF4 / CSTRIDE)                 // 128
#define SITER ((EPS4 + NTHR - 1) / NTHR)      // 49

__device__ __forceinline__ void upd2(unsigned* __restrict__ mn1, unsigned* __restrict__ mn2,
                                     int a, unsigned i) {
    if ((unsigned)a < NPB) {
        unsigned old = atomicMin(&mn1[a], i);
        unsigned c = (i < old) ? old : i;      // displaced value or losing insert
        atomicMin(&mn2[a], c);                 // c==0xFFFFFFFF is a value no-op: no branch
    }
}

__device__ __forceinline__ void proc(unsigned* __restrict__ mn1, unsigned* __restrict__ mn2,
                                     int lo, int4 p, int g /* global int4 index */) {
    // int4 g holds edges 2g (p.x,p.y) and 2g+1 (p.z,p.w)
    unsigned ia0 = (unsigned)(2 * g);
    unsigned ib0 = (unsigned)(2 * g + N_EDGES);
    upd2(mn1, mn2, p.x - lo, ia0);
    upd2(mn1, mn2, p.y - lo, ib0);
    upd2(mn1, mn2, p.z - lo, ia0 + 1u);
    upd2(mn1, mn2, p.w - lo, ib0 + 1u);
}

// Fused copy + LDS 2-min scan. NP=16 via 100KB LDS (1 block/CU): halves the
// partition amplification (wave-probe issues + edge re-reads) that tracked
// the scan's ~80us additive cost across r9-r13. Copy unrolled 8-deep so
// 16 waves/CU keep the same in-flight copy bytes as r11's 32 waves.
__global__ __launch_bounds__(NTHR) void fused_copy_scan(const float4* __restrict__ src,
                                                        float4* __restrict__ dst,
                                                        const int4* __restrict__ edges4,
                                                        unsigned long long* __restrict__ W) {
    __shared__ unsigned mn1[NPB];
    __shared__ unsigned mn2[NPB];

    int b  = blockIdx.x;
    int ep = b & 15;                 // slice
    int np = b >> 4;                 // node part 0..15
    int lo = np * NPB;
    int t  = threadIdx.x;

    for (int j = t; j < NPB; j += NTHR) { mn1[j] = 0xFFFFFFFFu; mn2[j] = 0xFFFFFFFFu; }
    __syncthreads();

    int q0 = ep * EPS4;              // slice start, int4 units
    int cbase = b * NTHR + t;        // copy index, stride CSTRIDE

    #pragma unroll 8
    for (int j = 0; j < CITER; ++j) {
        int ci = cbase + j * CSTRIDE;
        float4 v = src[ci];
        int k = t + j * NTHR;
        bool have = (j < SITER) && (k < EPS4);
        int4 p;
        if (have) p = edges4[q0 + k];
        dst[ci] = v;
        if (have) proc(mn1, mn2, lo, p, q0 + k);
    }
    __syncthreads();

    for (int j = t; j < NPB; j += NTHR) {
        int n = lo + j;
        if (n < N_PTS)
            W[(size_t)ep * N_PTS + n] =
                ((unsigned long long)mn2[j] << 32) | (unsigned long long)mn1[j];
    }
}

__device__ __forceinline__ int quant6(float d) {
    // match jnp: clip(round((d + 1)/2 * 63), 0, 63); jnp.round = half-to-even -> rintf
    float x = ((d + 1.0f) / 2.0f) * 63.0f;
    float r = rintf(x);
    r = fminf(fmaxf(r, 0.0f), 63.0f);
    return (int)r;
}

__global__ void finalize(const float* __restrict__ pts, const float* __restrict__ tex,
                         const int2* __restrict__ edges,
                         const unsigned long long* __restrict__ W,
                         float* __restrict__ out) {
    int n = blockIdx.x * blockDim.x + threadIdx.x;
    if (n >= N_PTS) return;

    // merge EP per-slice (m1,m2) pairs -> global two smallest (all indices distinct)
    unsigned int k1 = 0xFFFFFFFFu, k2 = 0xFFFFFFFFu;
    #pragma unroll
    for (int s = 0; s < EP; ++s) {
        unsigned long long pr = W[(size_t)s * N_PTS + n];
        unsigned int m1 = (unsigned int)(pr & 0xFFFFFFFFu);
        unsigned int m2 = (unsigned int)(pr >> 32);
        if (m1 < k1) { k2 = k1; k1 = m1; } else if (m1 < k2) { k2 = m1; }
        if (m2 < k2 && m2 > k1) { k2 = m2; }
    }

    float px = pts[2 * n], py = pts[2 * n + 1];
    int t = (tex[n] > 0.7f) ? 1 : 0;

    int v0x = 0, v0y = 0, t0 = 0, v1x = 0, v1y = 0, t1 = 0;

    if (k1 < 2u * N_EDGES) {
        int k = (int)k1;
        int2 e = edges[(k < N_EDGES) ? k : (k - N_EDGES)];
        int dst = (k < N_EDGES) ? e.y : e.x;
        v0x = quant6(pts[2 * dst] - px);
        v0y = quant6(pts[2 * dst + 1] - py);
        t0 = (tex[dst] > 0.7f) ? 1 : 0;
    }
    if (k2 < 2u * N_EDGES) {
        int k = (int)k2;
        int2 e = edges[(k < N_EDGES) ? k : (k - N_EDGES)];
        int dst = (k < N_EDGES) ? e.y : e.x;
        v1x = quant6(pts[2 * dst] - px);
        v1y = quant6(pts[2 * dst + 1] - py);
        t1 = (tex[dst] > 0.7f) ? 1 : 0;
    }

    // hash keeps only cols 0..4 (col4 masked to 3 bits); each rel-variant
    // appears 6 times in rel_all (2 builds x 3 identity-rolls / 3 swap-rolls).
    int h_id = t | (v0x << 6) | (v0y << 12) | (t0 << 18) | ((v1x & 7) << 24);
    int h_sw = t | (v1x << 6) | (v1y << 12) | (t1 << 18) | ((v0x & 7) << 24);

    atomicAdd(&out[h_id], 6.0f);
    atomicAdd(&out[h_sw], 6.0f);
}

extern "C" void kernel_launch(void* const* d_in, const int* in_sizes, int n_in,
                              void* d_out, int out_size, void* d_ws, size_t ws_size,
                              hipStream_t stream) {
    const float* pts   = (const float*)d_in[0];
    const float* tex   = (const float*)d_in[1];
    const int2*  edges = (const int2*)d_in[2];   // int64 in ref -> int32 on device
    const float* mem   = (const float*)d_in[3];
    float*       out   = (float*)d_out;

    unsigned long long* W = (unsigned long long*)d_ws;   // 16 * 200K * 8B = 25.6 MB

    fused_copy_scan<<<NBLK, NTHR, 0, stream>>>(
        (const float4*)mem, (float4*)out, (const int4*)edges, W);
    finalize<<<(N_PTS + 255) / 256, 256, 0, stream>>>(pts, tex, edges, W, out);
}